// Round 10
// baseline (433.445 us; speedup 1.0000x reference)
//
#include <hip/hip_runtime.h>
#include <hip/hip_bf16.h>

#define N 8192
#define IN_F 512
#define OUT_F 64
#define S_SPLIT 16
#define JT (N / S_SPLIT)   // 512 columns per split
#define LOG2E 1.4426950408889634f

typedef __attribute__((ext_vector_type(8))) short short8;
typedef __attribute__((ext_vector_type(4))) float floatx4;
typedef __attribute__((ext_vector_type(4))) int intx4;
typedef unsigned long long ull;

__device__ inline short f2bf(float x) {
    __hip_bfloat16 b = __float2bfloat16(x);
    return __builtin_bit_cast(short, b);
}

// K0: pack adjacency int32 {0,1} -> bitmask via ballot (proven R5 kernel).
__global__ __launch_bounds__(256) void k_pack(const int* __restrict__ adj,
                                              unsigned* __restrict__ mask) {
    int wv = (blockIdx.x * 256 + threadIdx.x) >> 6;
    int lane = threadIdx.x & 63;
    const int* p = adj + (size_t)wv * 512 + lane;
    ull m0 = __ballot(p[0]   > 0);
    ull m1 = __ballot(p[64]  > 0);
    ull m2 = __ballot(p[128] > 0);
    ull m3 = __ballot(p[192] > 0);
    ull m4 = __ballot(p[256] > 0);
    ull m5 = __ballot(p[320] > 0);
    ull m6 = __ballot(p[384] > 0);
    ull m7 = __ballot(p[448] > 0);
    if (lane < 16) {
        ull s0 = (lane & 2) ? m1 : m0;
        ull s1 = (lane & 2) ? m3 : m2;
        ull s2 = (lane & 2) ? m5 : m4;
        ull s3 = (lane & 2) ? m7 : m6;
        ull t0 = (lane & 4) ? s1 : s0;
        ull t1 = (lane & 4) ? s3 : s2;
        ull u  = (lane & 8) ? t1 : t0;
        unsigned dw = (lane & 1) ? (unsigned)(u >> 32) : (unsigned)u;
        mask[wv * 16 + lane] = dw;
    }
}

// K1a: W [512][64] fp32 -> WT [64][512] bf16
__global__ void k_wt(const float* __restrict__ W, short* __restrict__ WT) {
    int idx = blockIdx.x * 256 + threadIdx.x;
    int k = idx >> 6, f = idx & 63;
    WT[f * IN_F + k] = f2bf(W[k * OUT_F + f]);
}

// K1: WH = h @ W via bf16 MFMA. Epilogue: WHbT + the four exp vectors
// P1=exp(wh1), p1=exp(.01 wh1), P2=exp(wh2), p2=exp(.01 wh2).
__global__ __launch_bounds__(64) void k_wh(const float* __restrict__ h,
                                           const short* __restrict__ WT,
                                           const float* __restrict__ a,
                                           short* __restrict__ WHbT,
                                           float* __restrict__ P1,
                                           float* __restrict__ p1,
                                           float* __restrict__ P2,
                                           float* __restrict__ p2) {
    __shared__ float tile[OUT_F][17];
    int lane = threadIdx.x;
    int n = lane & 15, q = lane >> 4;
    int i0 = blockIdx.x * 16;
    int rowA = i0 + n;
    const float* hp = h + (size_t)rowA * IN_F + q * 8;
    floatx4 acc[4] = {};
    for (int k0 = 0; k0 < IN_F; k0 += 32) {
        floatx4 h0 = *(const floatx4*)(hp + k0);
        floatx4 h1 = *(const floatx4*)(hp + k0 + 4);
        short8 af;
#pragma unroll
        for (int j = 0; j < 4; j++) { af[j] = f2bf(h0[j]); af[j + 4] = f2bf(h1[j]); }
#pragma unroll
        for (int b = 0; b < 4; b++) {
            short8 bf_ = *(const short8*)(WT + (b * 16 + n) * IN_F + k0 + q * 8);
            acc[b] = __builtin_amdgcn_mfma_f32_16x16x32_bf16(af, bf_, acc[b], 0, 0, 0);
        }
    }
#pragma unroll
    for (int b = 0; b < 4; b++)
#pragma unroll
        for (int r = 0; r < 4; r++)
            tile[b * 16 + n][q * 4 + r] = acc[b][r];
    float a1v[4], a2v[4];
#pragma unroll
    for (int b = 0; b < 4; b++) { a1v[b] = a[b * 16 + n]; a2v[b] = a[OUT_F + b * 16 + n]; }
#pragma unroll
    for (int r = 0; r < 4; r++) {
        float s1 = 0.f, s2 = 0.f;
#pragma unroll
        for (int b = 0; b < 4; b++) { s1 += acc[b][r] * a1v[b]; s2 += acc[b][r] * a2v[b]; }
#pragma unroll
        for (int m = 1; m <= 8; m <<= 1) {
            s1 += __shfl_xor(s1, m, 64);
            s2 += __shfl_xor(s2, m, 64);
        }
        if (n == 0) {
            int i = i0 + q * 4 + r;
            P1[i] = __builtin_amdgcn_exp2f(LOG2E * s1);
            p1[i] = __builtin_amdgcn_exp2f(0.01f * LOG2E * s1);
            P2[i] = __builtin_amdgcn_exp2f(LOG2E * s2);
            p2[i] = __builtin_amdgcn_exp2f(0.01f * LOG2E * s2);
        }
    }
    __syncthreads();
    const float* tc = tile[lane];
    short8 s0, s1v;
#pragma unroll
    for (int k = 0; k < 8; k++) { s0[k] = f2bf(tc[k]); s1v[k] = f2bf(tc[k + 8]); }
    *(short8*)(WHbT + (size_t)lane * N + i0) = s0;
    *(short8*)(WHbT + (size_t)lane * N + i0 + 8) = s1v;
}

// K1c: reshape WHbT -> BP (B-fragment-packed, R9-proven).
__global__ __launch_bounds__(256) void k_bp(const short* __restrict__ WHbT,
                                            short* __restrict__ BP) {
    int g = blockIdx.x;
    int b = threadIdx.x >> 6;
    int lane = threadIdx.x & 63;
    int n = lane & 15, q = lane >> 4;
    short8 v = *(const short8*)(WHbT + (size_t)(b * 16 + n) * N + g * 32 + q * 8);
    *(short8*)(BP + ((size_t)(g * 4 + b) * 64 + lane) * 8) = v;
}

// K2: masked attention + (P @ WH) partials. Light waves (rf=1, 16 rows/wave),
// grid (128,16) = 8192 waves. Inner element = mul,mul,max,cndmask (no exp!).
// bf16 pack = round-half-up + v_perm. den via ones-MFMA.
__global__ __launch_bounds__(256, 4) void k_attn(const unsigned* __restrict__ maskb,
                                                 const short* __restrict__ BP,
                                                 const float* __restrict__ P1,
                                                 const float* __restrict__ p1,
                                                 const float* __restrict__ P2,
                                                 const float* __restrict__ p2,
                                                 float* __restrict__ num_part,
                                                 float* __restrict__ den_part) {
    int tid = threadIdx.x;
    int w = tid >> 6;
    int lane = tid & 63;
    int n = lane & 15, q = lane >> 4, qs = q * 8;
    int split = blockIdx.y;
    int j0 = split * JT;
    int i0 = blockIdx.x * 64 + w * 16;
    int row = i0 + n;

    float P1f = P1[row], p1f = p1[row];
    const unsigned* mrow = maskb + (size_t)row * 256 + split * 16;  // 16 dwords, 1 line
    const short8* bp = (const short8*)BP + (size_t)split * 4096 + lane;
    const float* P2p = P2 + j0 + qs;
    const float* p2p = p2 + j0 + qs;

    floatx4 acc[4] = {};
    floatx4 accd = {};
    short8 ones;
#pragma unroll
    for (int k = 0; k < 8; k++) ones[k] = (short)0x3F80;   // bf16 1.0

    // prefetch s = 0
    short8 bfr[4];
#pragma unroll
    for (int b = 0; b < 4; b++) bfr[b] = bp[b * 64];
    floatx4 Pc0 = *(const floatx4*)(P2p);
    floatx4 Pc1 = *(const floatx4*)(P2p + 4);
    floatx4 pc0 = *(const floatx4*)(p2p);
    floatx4 pc1 = *(const floatx4*)(p2p + 4);

    for (int s = 0; s < 16; s++) {
        int sn = (s + 1) & 15;                 // wraps on last iter (harmless)
        short8 nb[4];
#pragma unroll
        for (int b = 0; b < 4; b++) nb[b] = bp[sn * 256 + b * 64];
        floatx4 nP0 = *(const floatx4*)(P2p + sn * 32);
        floatx4 nP1 = *(const floatx4*)(P2p + sn * 32 + 4);
        floatx4 np0 = *(const floatx4*)(p2p + sn * 32);
        floatx4 np1 = *(const floatx4*)(p2p + sn * 32 + 4);

        unsigned mds = mrow[s] >> qs;
        float pv[8];
#pragma unroll
        for (int jj = 0; jj < 8; jj++) {
            float hv = P1f * ((jj < 4) ? Pc0[jj] : Pc1[jj - 4]);
            float lv = p1f * ((jj < 4) ? pc0[jj] : pc1[jj - 4]);
            float mx = fmaxf(hv, lv);          // = exp(leaky_relu(wh1+wh2))
            pv[jj] = (mds & (1u << jj)) ? mx : 0.f;
        }
        intx4 ai;
#pragma unroll
        for (int k = 0; k < 4; k++) {
            unsigned u0 = __builtin_bit_cast(unsigned, pv[2 * k]) + 0x8000u;
            unsigned u1 = __builtin_bit_cast(unsigned, pv[2 * k + 1]) + 0x8000u;
            ai[k] = (int)__builtin_amdgcn_perm(u1, u0, 0x07060302u);  // hi16(u1)|hi16(u0)
        }
        short8 af = __builtin_bit_cast(short8, ai);
#pragma unroll
        for (int b = 0; b < 4; b++)
            acc[b] = __builtin_amdgcn_mfma_f32_16x16x32_bf16(af, bfr[b], acc[b], 0, 0, 0);
        accd = __builtin_amdgcn_mfma_f32_16x16x32_bf16(af, ones, accd, 0, 0, 0);

#pragma unroll
        for (int b = 0; b < 4; b++) bfr[b] = nb[b];
        Pc0 = nP0; Pc1 = nP1; pc0 = np0; pc1 = np1;
    }

    // den (all cols of accd equal): C/D row = q*4+r
    if (n == 0) {
#pragma unroll
        for (int r = 0; r < 4; r++)
            den_part[(size_t)split * N + i0 + q * 4 + r] = accd[r];
    }
    // num: row = q*4+r, col = b*16+n
    float* np_ = num_part + (size_t)split * N * OUT_F;
#pragma unroll
    for (int b = 0; b < 4; b++)
#pragma unroll
        for (int r = 0; r < 4; r++)
            np_[(size_t)(i0 + q * 4 + r) * OUT_F + b * 16 + n] = acc[b][r];
}

// K3: out = elu( (Σ num_part) / (Σ den_part) )
__global__ void k_final(const float* __restrict__ num_part,
                        const float* __restrict__ den_part,
                        float* __restrict__ out) {
    int idx = blockIdx.x * 256 + threadIdx.x;
    int row = idx >> 6;
    float s = 0.f, d = 0.f;
#pragma unroll
    for (int sp = 0; sp < S_SPLIT; sp++) {
        s += num_part[(size_t)sp * N * OUT_F + idx];
        d += den_part[sp * N + row];
    }
    float x = s / d;
    out[idx] = (x > 0.f) ? x : (__expf(x) - 1.f);
}

extern "C" void kernel_launch(void* const* d_in, const int* in_sizes, int n_in,
                              void* d_out, int out_size, void* d_ws, size_t ws_size,
                              hipStream_t stream) {
    const float* h = (const float*)d_in[0];
    const int* adj = (const int*)d_in[1];
    const float* W = (const float*)d_in[2];
    const float* a = (const float*)d_in[3];
    float* out = (float*)d_out;

    char* ws = (char*)d_ws;
    short* WHbT     = (short*)(ws);                                   // 1 MB
    short* WT       = (short*)(ws + (size_t)(1 << 20));               // 64 KB
    float* P1       = (float*)(ws + (size_t)(1 << 20) + (64 << 10));  // 32 KB
    float* p1       = P1 + N;                                         // 32 KB
    float* P2       = p1 + N;                                         // 32 KB
    float* p2       = P2 + N;                                         // 32 KB
    unsigned* maskb = (unsigned*)(ws + (size_t)(2 << 20));            // 8 MB
    short* BP       = (short*)(ws + (size_t)(12 << 20));              // 1 MB
    float* num_p    = (float*)(ws + (size_t)(16 << 20));              // 32 MB
    float* den_p    = (float*)(ws + (size_t)(48 << 20));              // 512 KB

    k_pack<<<dim3((N / 32) * (N / 256) * 4), dim3(256), 0, stream>>>(adj, maskb);
    k_wt<<<dim3(128), dim3(256), 0, stream>>>(W, WT);
    k_wh<<<dim3(N / 16), dim3(64), 0, stream>>>(h, WT, a, WHbT, P1, p1, P2, p2);
    k_bp<<<dim3(256), dim3(256), 0, stream>>>(WHbT, BP);
    k_attn<<<dim3(N / 64, S_SPLIT), dim3(256), 0, stream>>>(maskb, BP, P1, p1, P2, p2,
                                                            num_p, den_p);
    k_final<<<dim3((N * OUT_F) / 256), dim3(256), 0, stream>>>(num_p, den_p, out);
}